// Round 1
// baseline (204.666 us; speedup 1.0000x reference)
//
#include <hip/hip_runtime.h>

#define F_EPS 1e-12f
#define F_DAMPING 0.95f
#define N_ITER 6

struct Params {
    float R[9];    // R[k*3+j] = surface_tf[k][j]
    float tv[3];   // surface_tf[k][3]
    float C_eff;
    float s2;
    float scale;
    float half_d2; // (diameter/2)^2
};

// One-thread kernel: derive scalar params + write surface_tf / next_tf outputs.
__global__ void setup_kernel(const float* __restrict__ tf,
                             const float* __restrict__ diameter,
                             const float* __restrict__ C,
                             const float* __restrict__ anchors,
                             const float* __restrict__ scale,
                             const unsigned char* __restrict__ normalize,
                             float* __restrict__ out_tail,   // 32 floats: surface_tf, next_tf
                             Params* __restrict__ params)
{
#pragma clang fp contract(off)
    if (threadIdx.x != 0 || blockIdx.x != 0) return;
    float d  = diameter[0];
    float c  = C[0];
    float sc = scale[0];
    bool  nrm = (normalize[0] != 0);
    float C_eff = nrm ? (c * 2.0f / d) : c;
    float s2 = sc * sc;
    float hr = d * 0.5f;
    float hr2 = hr * hr;
    // extent = sag(hr2)
    float u = hr2 / s2;
    float root = sqrtf(fmaxf(1.0f - (C_eff * C_eff) * u, F_EPS));
    float extent = sc * C_eff * u / (1.0f + root);
    float a0 = anchors[0], a1 = anchors[1];
    float dx0 = -a0 * extent;
    float dx1 = (a1 - a0) * extent;
    // surface_tf = tf @ Tx(dx0): only column 3 changes.
    for (int i = 0; i < 4; ++i) {
        for (int j = 0; j < 4; ++j) {
            float v = tf[i * 4 + j];
            float sv = (j == 3) ? (tf[i * 4 + 0] * dx0 + v) : v;
            float nv = (j == 3) ? (tf[i * 4 + 0] * dx1 + v) : v;
            out_tail[i * 4 + j]      = sv;
            out_tail[16 + i * 4 + j] = nv;
        }
    }
    for (int k = 0; k < 3; ++k) {
        for (int j = 0; j < 3; ++j)
            params->R[k * 3 + j] = tf[k * 4 + j];           // rotation part unchanged
        params->tv[k] = tf[k * 4 + 0] * dx0 + tf[k * 4 + 3]; // translated column
    }
    params->C_eff   = C_eff;
    params->s2      = s2;
    params->scale   = sc;
    params->half_d2 = hr2;
}

// Main kernel: 4 rays per thread, all global traffic as float4.
__launch_bounds__(256)
__global__ void trace_kernel(const float* __restrict__ P,
                             const float* __restrict__ V,
                             const Params* __restrict__ pp,
                             float* __restrict__ out,
                             int n)
{
#pragma clang fp contract(off)
    int tid = blockIdx.x * blockDim.x + threadIdx.x;
    int base = tid * 4;
    if (base >= n) return;

    // Uniform param loads (compiler emits scalar loads).
    float R0 = pp->R[0], R1 = pp->R[1], R2 = pp->R[2];
    float R3 = pp->R[3], R4 = pp->R[4], R5 = pp->R[5];
    float R6 = pp->R[6], R7 = pp->R[7], R8 = pp->R[8];
    float tv0 = pp->tv[0], tv1 = pp->tv[1], tv2 = pp->tv[2];
    float C_eff = pp->C_eff, s2 = pp->s2, scale = pp->scale, half_d2 = pp->half_d2;
    float ce2 = C_eff * C_eff;
    float sC  = scale * C_eff;

    float Px[4], Py[4], Pz[4], Vx[4], Vy[4], Vz[4];
    bool full = (base + 3 < n) || (base + 4 == n) || (base + 4 <= n);
    if (base + 4 <= n) {
        const float4* P4 = reinterpret_cast<const float4*>(P + (size_t)base * 3);
        const float4* V4 = reinterpret_cast<const float4*>(V + (size_t)base * 3);
        float4 pa = P4[0], pb = P4[1], pc = P4[2];
        float4 va = V4[0], vb = V4[1], vc = V4[2];
        Px[0] = pa.x; Py[0] = pa.y; Pz[0] = pa.z;
        Px[1] = pa.w; Py[1] = pb.x; Pz[1] = pb.y;
        Px[2] = pb.z; Py[2] = pb.w; Pz[2] = pc.x;
        Px[3] = pc.y; Py[3] = pc.z; Pz[3] = pc.w;
        Vx[0] = va.x; Vy[0] = va.y; Vz[0] = va.z;
        Vx[1] = va.w; Vy[1] = vb.x; Vz[1] = vb.y;
        Vx[2] = vb.z; Vy[2] = vb.w; Vz[2] = vc.x;
        Vx[3] = vc.y; Vy[3] = vc.z; Vz[3] = vc.w;
    } else {
        for (int r = 0; r < 4; ++r) {
            int i = base + r;
            if (i < n) {
                Px[r] = P[(size_t)i * 3 + 0]; Py[r] = P[(size_t)i * 3 + 1]; Pz[r] = P[(size_t)i * 3 + 2];
                Vx[r] = V[(size_t)i * 3 + 0]; Vy[r] = V[(size_t)i * 3 + 1]; Vz[r] = V[(size_t)i * 3 + 2];
            } else {
                Px[r] = 0.0f; Py[r] = 0.0f; Pz[r] = 0.0f;
                Vx[r] = 1.0f; Vy[r] = 0.0f; Vz[r] = 0.0f;
            }
        }
    }
    (void)full;

    float tres[4], nxo[4], nyo[4], nzo[4], val[4];
#pragma unroll
    for (int r = 0; r < 4; ++r) {
        float px0 = Px[r] - tv0, py0 = Py[r] - tv1, pz0 = Pz[r] - tv2;
        float Plx = px0 * R0 + py0 * R3 + pz0 * R6;
        float Ply = px0 * R1 + py0 * R4 + pz0 * R7;
        float Plz = px0 * R2 + py0 * R5 + pz0 * R8;
        float vx = Vx[r] * R0 + Vy[r] * R3 + Vz[r] * R6;
        float vy = Vx[r] * R1 + Vy[r] * R4 + Vz[r] * R7;
        float vz = Vx[r] * R2 + Vy[r] * R5 + Vz[r] * R8;
        float safe_vx = (fabsf(vx) > F_EPS) ? vx : F_EPS;
        float t = (-Plx) / safe_vx;
#pragma unroll
        for (int it = 0; it < N_ITER; ++it) {
            float pxx = Plx + t * vx;
            float py  = Ply + t * vy;
            float pz  = Plz + t * vz;
            float r2  = py * py + pz * pz;
            float u   = r2 / s2;
            float root = sqrtf(fmaxf(1.0f - ce2 * u, F_EPS));
            float F = sC * u / (1.0f + root) - pxx;
            float k = C_eff / (scale * root);
            float gy = k * py, gz = k * pz;
            float dF = gy * vy + gz * vz - vx;
            dF = (fabsf(dF) > F_EPS) ? dF : F_EPS;
            t = t - F_DAMPING * F / dF;
        }
        float pxx = Plx + t * vx;
        float py  = Ply + t * vy;
        float pz  = Plz + t * vz;
        float r2  = py * py + pz * pz;
        float u   = r2 / s2;
        float root = sqrtf(fmaxf(1.0f - ce2 * u, F_EPS));
        float F = sC * u / (1.0f + root) - pxx;
        float k = C_eff / (scale * root);
        float gy = k * py, gz = k * pz;
        // n_local = (-1, gy, gz) / ||.||, then @ R^T
        float nn = sqrtf(1.0f + gy * gy + gz * gz);
        float nlx = (-1.0f) / nn, nly = gy / nn, nlz = gz / nn;
        nxo[r] = nlx * R0 + nly * R1 + nlz * R2;
        nyo[r] = nlx * R3 + nly * R4 + nlz * R5;
        nzo[r] = nlx * R6 + nly * R7 + nlz * R8;
        tres[r] = t;
        val[r]  = ((r2 <= half_d2) && (fabsf(F) < 1e-4f)) ? 1.0f : 0.0f;
    }

    float* t_out = out;
    float* n_out = out + (size_t)n;
    float* v_out = out + (size_t)n * 4;
    if (base + 4 <= n) {
        *reinterpret_cast<float4*>(t_out + base) = make_float4(tres[0], tres[1], tres[2], tres[3]);
        float4* N4 = reinterpret_cast<float4*>(n_out + (size_t)base * 3);
        N4[0] = make_float4(nxo[0], nyo[0], nzo[0], nxo[1]);
        N4[1] = make_float4(nyo[1], nzo[1], nxo[2], nyo[2]);
        N4[2] = make_float4(nzo[2], nxo[3], nyo[3], nzo[3]);
        *reinterpret_cast<float4*>(v_out + base) = make_float4(val[0], val[1], val[2], val[3]);
    } else {
        for (int r = 0; r < 4; ++r) {
            int i = base + r;
            if (i < n) {
                t_out[i] = tres[r];
                n_out[(size_t)i * 3 + 0] = nxo[r];
                n_out[(size_t)i * 3 + 1] = nyo[r];
                n_out[(size_t)i * 3 + 2] = nzo[r];
                v_out[i] = val[r];
            }
        }
    }
}

extern "C" void kernel_launch(void* const* d_in, const int* in_sizes, int n_in,
                              void* d_out, int out_size, void* d_ws, size_t ws_size,
                              hipStream_t stream) {
    const float* P  = (const float*)d_in[0];
    const float* V  = (const float*)d_in[1];
    const float* tf = (const float*)d_in[2];
    const float* diameter = (const float*)d_in[3];
    const float* C  = (const float*)d_in[4];
    const float* anchors = (const float*)d_in[5];
    const float* scale = (const float*)d_in[6];
    const unsigned char* normalize = (const unsigned char*)d_in[7];
    int n = in_sizes[0] / 3;
    float* out = (float*)d_out;
    float* out_tail = out + (size_t)n * 5;   // surface_tf (16) + next_tf (16)
    Params* params = (Params*)d_ws;

    setup_kernel<<<1, 1, 0, stream>>>(tf, diameter, C, anchors, scale, normalize,
                                      out_tail, params);
    int threads = 256;
    int nthreads = (n + 3) / 4;
    int blocks = (nthreads + threads - 1) / threads;
    trace_kernel<<<blocks, threads, 0, stream>>>(P, V, params, out, n);
}

// Round 2
// 182.578 us; speedup vs baseline: 1.1210x; 1.1210x over previous
//
#include <hip/hip_runtime.h>

#define F_EPS 1e-12f
#define F_DAMPING 0.95f
#define N_ITER 6

struct Params {
    float R[9];    // R[k*3+j] = surface_tf[k][j]
    float tv[3];   // surface_tf[k][3]
    float C_eff;
    float s2;
    float scale;
    float half_d2; // (diameter/2)^2
    float inv_s2;  // 1/s2
};

// One-thread kernel: derive scalar params + write surface_tf / next_tf outputs.
__global__ void setup_kernel(const float* __restrict__ tf,
                             const float* __restrict__ diameter,
                             const float* __restrict__ C,
                             const float* __restrict__ anchors,
                             const float* __restrict__ scale,
                             const unsigned char* __restrict__ normalize,
                             float* __restrict__ out_tail,   // 32 floats: surface_tf, next_tf
                             Params* __restrict__ params)
{
#pragma clang fp contract(off)
    if (threadIdx.x != 0 || blockIdx.x != 0) return;
    float d  = diameter[0];
    float c  = C[0];
    float sc = scale[0];
    bool  nrm = (normalize[0] != 0);
    float C_eff = nrm ? (c * 2.0f / d) : c;
    float s2 = sc * sc;
    float hr = d * 0.5f;
    float hr2 = hr * hr;
    // extent = sag(hr2)
    float u = hr2 / s2;
    float root = sqrtf(fmaxf(1.0f - (C_eff * C_eff) * u, F_EPS));
    float extent = sc * C_eff * u / (1.0f + root);
    float a0 = anchors[0], a1 = anchors[1];
    float dx0 = -a0 * extent;
    float dx1 = (a1 - a0) * extent;
    // surface_tf = tf @ Tx(dx0): only column 3 changes.
    for (int i = 0; i < 4; ++i) {
        for (int j = 0; j < 4; ++j) {
            float v = tf[i * 4 + j];
            float sv = (j == 3) ? (tf[i * 4 + 0] * dx0 + v) : v;
            float nv = (j == 3) ? (tf[i * 4 + 0] * dx1 + v) : v;
            out_tail[i * 4 + j]      = sv;
            out_tail[16 + i * 4 + j] = nv;
        }
    }
    for (int k = 0; k < 3; ++k) {
        for (int j = 0; j < 3; ++j)
            params->R[k * 3 + j] = tf[k * 4 + j];           // rotation part unchanged
        params->tv[k] = tf[k * 4 + 0] * dx0 + tf[k * 4 + 3]; // translated column
    }
    params->C_eff   = C_eff;
    params->s2      = s2;
    params->scale   = sc;
    params->half_d2 = hr2;
    params->inv_s2  = 1.0f / s2;
}

// Main kernel: 4 rays per thread, all global traffic as float4.
// Newton loop uses hw rcp/rsq (~1 ulp) + explicit fmaf; epilogue stays
// precise (contract off) to keep the reference operation order for the
// valid = |F|<1e-4 decision and the checked outputs.
__launch_bounds__(256)
__global__ void trace_kernel(const float* __restrict__ P,
                             const float* __restrict__ V,
                             const Params* __restrict__ pp,
                             float* __restrict__ out,
                             int n)
{
#pragma clang fp contract(off)
    int tid = blockIdx.x * blockDim.x + threadIdx.x;
    int base = tid * 4;
    if (base >= n) return;

    // Uniform param loads (compiler emits scalar loads).
    float R0 = pp->R[0], R1 = pp->R[1], R2 = pp->R[2];
    float R3 = pp->R[3], R4 = pp->R[4], R5 = pp->R[5];
    float R6 = pp->R[6], R7 = pp->R[7], R8 = pp->R[8];
    float tv0 = pp->tv[0], tv1 = pp->tv[1], tv2 = pp->tv[2];
    float C_eff = pp->C_eff, s2 = pp->s2, scale = pp->scale, half_d2 = pp->half_d2;
    float inv_s2 = pp->inv_s2;
    float ce2 = C_eff * C_eff;
    float sC  = scale * C_eff;
    // Folded constants for the fast Newton loop:
    float a_num = sC * inv_s2;          // F numerator coeff: a_num * r2
    float ce2s  = ce2 * inv_s2;         // m = 1 - ce2s * r2
    float Cs    = C_eff / scale;        // k = Cs * rsq(m)

    float Px[4], Py[4], Pz[4], Vx[4], Vy[4], Vz[4];
    if (base + 4 <= n) {
        const float4* P4 = reinterpret_cast<const float4*>(P + (size_t)base * 3);
        const float4* V4 = reinterpret_cast<const float4*>(V + (size_t)base * 3);
        float4 pa = P4[0], pb = P4[1], pc = P4[2];
        float4 va = V4[0], vb = V4[1], vc = V4[2];
        Px[0] = pa.x; Py[0] = pa.y; Pz[0] = pa.z;
        Px[1] = pa.w; Py[1] = pb.x; Pz[1] = pb.y;
        Px[2] = pb.z; Py[2] = pb.w; Pz[2] = pc.x;
        Px[3] = pc.y; Py[3] = pc.z; Pz[3] = pc.w;
        Vx[0] = va.x; Vy[0] = va.y; Vz[0] = va.z;
        Vx[1] = va.w; Vy[1] = vb.x; Vz[1] = vb.y;
        Vx[2] = vb.z; Vy[2] = vb.w; Vz[2] = vc.x;
        Vx[3] = vc.y; Vy[3] = vc.z; Vz[3] = vc.w;
    } else {
        for (int r = 0; r < 4; ++r) {
            int i = base + r;
            if (i < n) {
                Px[r] = P[(size_t)i * 3 + 0]; Py[r] = P[(size_t)i * 3 + 1]; Pz[r] = P[(size_t)i * 3 + 2];
                Vx[r] = V[(size_t)i * 3 + 0]; Vy[r] = V[(size_t)i * 3 + 1]; Vz[r] = V[(size_t)i * 3 + 2];
            } else {
                Px[r] = 0.0f; Py[r] = 0.0f; Pz[r] = 0.0f;
                Vx[r] = 1.0f; Vy[r] = 0.0f; Vz[r] = 0.0f;
            }
        }
    }

    float tres[4], nxo[4], nyo[4], nzo[4], val[4];
#pragma unroll
    for (int r = 0; r < 4; ++r) {
        float px0 = Px[r] - tv0, py0 = Py[r] - tv1, pz0 = Pz[r] - tv2;
        float Plx = px0 * R0 + py0 * R3 + pz0 * R6;
        float Ply = px0 * R1 + py0 * R4 + pz0 * R7;
        float Plz = px0 * R2 + py0 * R5 + pz0 * R8;
        float vx = Vx[r] * R0 + Vy[r] * R3 + Vz[r] * R6;
        float vy = Vx[r] * R1 + Vy[r] * R4 + Vz[r] * R7;
        float vz = Vx[r] * R2 + Vy[r] * R5 + Vz[r] * R8;
        float safe_vx = (fabsf(vx) > F_EPS) ? vx : F_EPS;
        float t = (-Plx) / safe_vx;

        // ---- fast Newton loop: hw rcp/rsq (1 ulp), explicit fmaf ----
#pragma unroll
        for (int it = 0; it < N_ITER; ++it) {
            float pxx = fmaf(t, vx, Plx);
            float py  = fmaf(t, vy, Ply);
            float pz  = fmaf(t, vz, Plz);
            float r2  = fmaf(py, py, pz * pz);
            float m   = fmaxf(fmaf(-ce2s, r2, 1.0f), F_EPS);
            float rsq = __builtin_amdgcn_rsqf(m);     // 1/sqrt(m), ~1 ulp
            float root = m * rsq;                      // sqrt(m)
            float k    = Cs * rsq;                     // C_eff/(scale*root)
            float ird  = __builtin_amdgcn_rcpf(1.0f + root);
            float F    = fmaf(a_num * r2, ird, -pxx);  // sag(r2) - p.x
            float gy = k * py, gz = k * pz;
            float dF = fmaf(gy, vy, fmaf(gz, vz, -vx));
            dF = (fabsf(dF) > F_EPS) ? dF : F_EPS;
            float idF = __builtin_amdgcn_rcpf(dF);
            t = fmaf(-F_DAMPING * F, idF, t);
        }

        // ---- precise epilogue (reference op order) ----
        float pxx = Plx + t * vx;
        float py  = Ply + t * vy;
        float pz  = Plz + t * vz;
        float r2  = py * py + pz * pz;
        float u   = r2 / s2;
        float root = sqrtf(fmaxf(1.0f - ce2 * u, F_EPS));
        float F = sC * u / (1.0f + root) - pxx;
        float k = C_eff / (scale * root);
        float gy = k * py, gz = k * pz;
        // n_local = (-1, gy, gz) / ||.||, then @ R^T
        float nn = sqrtf(1.0f + gy * gy + gz * gz);
        float nlx = (-1.0f) / nn, nly = gy / nn, nlz = gz / nn;
        nxo[r] = nlx * R0 + nly * R1 + nlz * R2;
        nyo[r] = nlx * R3 + nly * R4 + nlz * R5;
        nzo[r] = nlx * R6 + nly * R7 + nlz * R8;
        tres[r] = t;
        val[r]  = ((r2 <= half_d2) && (fabsf(F) < 1e-4f)) ? 1.0f : 0.0f;
    }

    float* t_out = out;
    float* n_out = out + (size_t)n;
    float* v_out = out + (size_t)n * 4;
    if (base + 4 <= n) {
        *reinterpret_cast<float4*>(t_out + base) = make_float4(tres[0], tres[1], tres[2], tres[3]);
        float4* N4 = reinterpret_cast<float4*>(n_out + (size_t)base * 3);
        N4[0] = make_float4(nxo[0], nyo[0], nzo[0], nxo[1]);
        N4[1] = make_float4(nyo[1], nzo[1], nxo[2], nyo[2]);
        N4[2] = make_float4(nzo[2], nxo[3], nyo[3], nzo[3]);
        *reinterpret_cast<float4*>(v_out + base) = make_float4(val[0], val[1], val[2], val[3]);
    } else {
        for (int r = 0; r < 4; ++r) {
            int i = base + r;
            if (i < n) {
                t_out[i] = tres[r];
                n_out[(size_t)i * 3 + 0] = nxo[r];
                n_out[(size_t)i * 3 + 1] = nyo[r];
                n_out[(size_t)i * 3 + 2] = nzo[r];
                v_out[i] = val[r];
            }
        }
    }
}

extern "C" void kernel_launch(void* const* d_in, const int* in_sizes, int n_in,
                              void* d_out, int out_size, void* d_ws, size_t ws_size,
                              hipStream_t stream) {
    const float* P  = (const float*)d_in[0];
    const float* V  = (const float*)d_in[1];
    const float* tf = (const float*)d_in[2];
    const float* diameter = (const float*)d_in[3];
    const float* C  = (const float*)d_in[4];
    const float* anchors = (const float*)d_in[5];
    const float* scale = (const float*)d_in[6];
    const unsigned char* normalize = (const unsigned char*)d_in[7];
    int n = in_sizes[0] / 3;
    float* out = (float*)d_out;
    float* out_tail = out + (size_t)n * 5;   // surface_tf (16) + next_tf (16)
    Params* params = (Params*)d_ws;

    setup_kernel<<<1, 1, 0, stream>>>(tf, diameter, C, anchors, scale, normalize,
                                      out_tail, params);
    int threads = 256;
    int nthreads = (n + 3) / 4;
    int blocks = (nthreads + threads - 1) / threads;
    trace_kernel<<<blocks, threads, 0, stream>>>(P, V, params, out, n);
}

// Round 3
// 180.509 us; speedup vs baseline: 1.1338x; 1.0115x over previous
//
#include <hip/hip_runtime.h>

#define F_EPS 1e-12f
#define F_DAMPING 0.95f
#define N_ITER 6

struct Params {
    float R[9];    // R[k*3+j] = surface_tf[k][j]
    float tv[3];   // surface_tf[k][3]
    float C_eff;
    float s2;
    float scale;
    float half_d2; // (diameter/2)^2
    float inv_s2;  // 1/s2
};

// One-thread kernel: derive scalar params + write surface_tf / next_tf outputs.
// Stays fully precise (contract off) — these 32 floats are checked outputs.
__global__ void setup_kernel(const float* __restrict__ tf,
                             const float* __restrict__ diameter,
                             const float* __restrict__ C,
                             const float* __restrict__ anchors,
                             const float* __restrict__ scale,
                             const unsigned char* __restrict__ normalize,
                             float* __restrict__ out_tail,   // 32 floats: surface_tf, next_tf
                             Params* __restrict__ params)
{
#pragma clang fp contract(off)
    if (threadIdx.x != 0 || blockIdx.x != 0) return;
    float d  = diameter[0];
    float c  = C[0];
    float sc = scale[0];
    bool  nrm = (normalize[0] != 0);
    float C_eff = nrm ? (c * 2.0f / d) : c;
    float s2 = sc * sc;
    float hr = d * 0.5f;
    float hr2 = hr * hr;
    // extent = sag(hr2)
    float u = hr2 / s2;
    float root = sqrtf(fmaxf(1.0f - (C_eff * C_eff) * u, F_EPS));
    float extent = sc * C_eff * u / (1.0f + root);
    float a0 = anchors[0], a1 = anchors[1];
    float dx0 = -a0 * extent;
    float dx1 = (a1 - a0) * extent;
    // surface_tf = tf @ Tx(dx0): only column 3 changes.
    for (int i = 0; i < 4; ++i) {
        for (int j = 0; j < 4; ++j) {
            float v = tf[i * 4 + j];
            float sv = (j == 3) ? (tf[i * 4 + 0] * dx0 + v) : v;
            float nv = (j == 3) ? (tf[i * 4 + 0] * dx1 + v) : v;
            out_tail[i * 4 + j]      = sv;
            out_tail[16 + i * 4 + j] = nv;
        }
    }
    for (int k = 0; k < 3; ++k) {
        for (int j = 0; j < 3; ++j)
            params->R[k * 3 + j] = tf[k * 4 + j];           // rotation part unchanged
        params->tv[k] = tf[k * 4 + 0] * dx0 + tf[k * 4 + 3]; // translated column
    }
    params->C_eff   = C_eff;
    params->s2      = s2;
    params->scale   = sc;
    params->half_d2 = hr2;
    params->inv_s2  = 1.0f / s2;
}

// Main kernel: 4 rays per thread, all global traffic as float4.
// it-loop OUTER / ray-loop INNER: all 4 Newton states live simultaneously
// so the scheduler must interleave 4 independent chains (ILP hides rcp/rsq
// latency). Fast hw rcp/rsq throughout; fp contraction allowed.
__launch_bounds__(256)
__global__ void trace_kernel(const float* __restrict__ P,
                             const float* __restrict__ V,
                             const Params* __restrict__ pp,
                             float* __restrict__ out,
                             int n)
{
    int tid = blockIdx.x * blockDim.x + threadIdx.x;
    int base = tid * 4;
    if (base >= n) return;

    // Uniform param loads (scalar).
    float R0 = pp->R[0], R1 = pp->R[1], R2 = pp->R[2];
    float R3 = pp->R[3], R4 = pp->R[4], R5 = pp->R[5];
    float R6 = pp->R[6], R7 = pp->R[7], R8 = pp->R[8];
    float tv0 = pp->tv[0], tv1 = pp->tv[1], tv2 = pp->tv[2];
    float C_eff = pp->C_eff, scale = pp->scale, half_d2 = pp->half_d2;
    float inv_s2 = pp->inv_s2;
    float ce2 = C_eff * C_eff;
    float sC  = scale * C_eff;
    float a_num = sC * inv_s2;          // F = a_num*r2/(1+root) - p.x
    float ce2s  = ce2 * inv_s2;         // m = 1 - ce2s*r2
    float Cs    = C_eff / scale;        // k = Cs * rsq(m)

    float Px[4], Py[4], Pz[4], Vx[4], Vy[4], Vz[4];
    if (base + 4 <= n) {
        const float4* P4 = reinterpret_cast<const float4*>(P + (size_t)base * 3);
        const float4* V4 = reinterpret_cast<const float4*>(V + (size_t)base * 3);
        float4 pa = P4[0], pb = P4[1], pc = P4[2];
        float4 va = V4[0], vb = V4[1], vc = V4[2];
        Px[0] = pa.x; Py[0] = pa.y; Pz[0] = pa.z;
        Px[1] = pa.w; Py[1] = pb.x; Pz[1] = pb.y;
        Px[2] = pb.z; Py[2] = pb.w; Pz[2] = pc.x;
        Px[3] = pc.y; Py[3] = pc.z; Pz[3] = pc.w;
        Vx[0] = va.x; Vy[0] = va.y; Vz[0] = va.z;
        Vx[1] = va.w; Vy[1] = vb.x; Vz[1] = vb.y;
        Vx[2] = vb.z; Vy[2] = vb.w; Vz[2] = vc.x;
        Vx[3] = vc.y; Vy[3] = vc.z; Vz[3] = vc.w;
    } else {
        for (int r = 0; r < 4; ++r) {
            int i = base + r;
            if (i < n) {
                Px[r] = P[(size_t)i * 3 + 0]; Py[r] = P[(size_t)i * 3 + 1]; Pz[r] = P[(size_t)i * 3 + 2];
                Vx[r] = V[(size_t)i * 3 + 0]; Vy[r] = V[(size_t)i * 3 + 1]; Vz[r] = V[(size_t)i * 3 + 2];
            } else {
                Px[r] = 0.0f; Py[r] = 0.0f; Pz[r] = 0.0f;
                Vx[r] = 1.0f; Vy[r] = 0.0f; Vz[r] = 0.0f;
            }
        }
    }

    // ---- transform to local frame (SoA state, all 4 rays live) ----
    float Plx[4], Ply[4], Plz[4], vx[4], vy[4], vz[4], t[4];
#pragma unroll
    for (int r = 0; r < 4; ++r) {
        float px0 = Px[r] - tv0, py0 = Py[r] - tv1, pz0 = Pz[r] - tv2;
        Plx[r] = px0 * R0 + py0 * R3 + pz0 * R6;
        Ply[r] = px0 * R1 + py0 * R4 + pz0 * R7;
        Plz[r] = px0 * R2 + py0 * R5 + pz0 * R8;
        vx[r] = Vx[r] * R0 + Vy[r] * R3 + Vz[r] * R6;
        vy[r] = Vx[r] * R1 + Vy[r] * R4 + Vz[r] * R7;
        vz[r] = Vx[r] * R2 + Vy[r] * R5 + Vz[r] * R8;
        float safe_vx = (fabsf(vx[r]) > F_EPS) ? vx[r] : F_EPS;
        t[r] = (-Plx[r]) * __builtin_amdgcn_rcpf(safe_vx);
    }

    // ---- Newton: it OUTER, ray INNER (4 independent chains interleave) ----
#pragma unroll
    for (int it = 0; it < N_ITER; ++it) {
#pragma unroll
        for (int r = 0; r < 4; ++r) {
            float pxx = fmaf(t[r], vx[r], Plx[r]);
            float py  = fmaf(t[r], vy[r], Ply[r]);
            float pz  = fmaf(t[r], vz[r], Plz[r]);
            float r2  = fmaf(py, py, pz * pz);
            float m   = fmaxf(fmaf(-ce2s, r2, 1.0f), F_EPS);
            float rsq = __builtin_amdgcn_rsqf(m);     // 1/sqrt(m)
            float root = m * rsq;                      // sqrt(m)
            float k    = Cs * rsq;
            float ird  = __builtin_amdgcn_rcpf(1.0f + root);
            float F    = fmaf(a_num * r2, ird, -pxx);
            float dF = fmaf(k * py, vy[r], fmaf(k * pz, vz[r], -vx[r]));
            dF = (fabsf(dF) > F_EPS) ? dF : F_EPS;
            t[r] = fmaf(-F_DAMPING * F, __builtin_amdgcn_rcpf(dF), t[r]);
        }
    }

    // ---- fast epilogue (rcp/rsq; same math, contraction allowed) ----
    float tres[4], nxo[4], nyo[4], nzo[4], val[4];
#pragma unroll
    for (int r = 0; r < 4; ++r) {
        float pxx = fmaf(t[r], vx[r], Plx[r]);
        float py  = fmaf(t[r], vy[r], Ply[r]);
        float pz  = fmaf(t[r], vz[r], Plz[r]);
        float r2  = fmaf(py, py, pz * pz);
        float m   = fmaxf(fmaf(-ce2s, r2, 1.0f), F_EPS);
        float rsq = __builtin_amdgcn_rsqf(m);
        float root = m * rsq;
        float k    = Cs * rsq;
        float ird  = __builtin_amdgcn_rcpf(1.0f + root);
        float F    = fmaf(a_num * r2, ird, -pxx);
        float gy = k * py, gz = k * pz;
        // n_local = (-1, gy, gz)/||.||  then @ R^T
        float nn2 = fmaf(gy, gy, fmaf(gz, gz, 1.0f));
        float irn = __builtin_amdgcn_rsqf(nn2);
        float nlx = -irn, nly = gy * irn, nlz = gz * irn;
        nxo[r] = nlx * R0 + nly * R1 + nlz * R2;
        nyo[r] = nlx * R3 + nly * R4 + nlz * R5;
        nzo[r] = nlx * R6 + nly * R7 + nlz * R8;
        tres[r] = t[r];
        val[r]  = ((r2 <= half_d2) && (fabsf(F) < 1e-4f)) ? 1.0f : 0.0f;
    }

    float* t_out = out;
    float* n_out = out + (size_t)n;
    float* v_out = out + (size_t)n * 4;
    if (base + 4 <= n) {
        *reinterpret_cast<float4*>(t_out + base) = make_float4(tres[0], tres[1], tres[2], tres[3]);
        float4* N4 = reinterpret_cast<float4*>(n_out + (size_t)base * 3);
        N4[0] = make_float4(nxo[0], nyo[0], nzo[0], nxo[1]);
        N4[1] = make_float4(nyo[1], nzo[1], nxo[2], nyo[2]);
        N4[2] = make_float4(nzo[2], nxo[3], nyo[3], nzo[3]);
        *reinterpret_cast<float4*>(v_out + base) = make_float4(val[0], val[1], val[2], val[3]);
    } else {
        for (int r = 0; r < 4; ++r) {
            int i = base + r;
            if (i < n) {
                t_out[i] = tres[r];
                n_out[(size_t)i * 3 + 0] = nxo[r];
                n_out[(size_t)i * 3 + 1] = nyo[r];
                n_out[(size_t)i * 3 + 2] = nzo[r];
                v_out[i] = val[r];
            }
        }
    }
}

extern "C" void kernel_launch(void* const* d_in, const int* in_sizes, int n_in,
                              void* d_out, int out_size, void* d_ws, size_t ws_size,
                              hipStream_t stream) {
    const float* P  = (const float*)d_in[0];
    const float* V  = (const float*)d_in[1];
    const float* tf = (const float*)d_in[2];
    const float* diameter = (const float*)d_in[3];
    const float* C  = (const float*)d_in[4];
    const float* anchors = (const float*)d_in[5];
    const float* scale = (const float*)d_in[6];
    const unsigned char* normalize = (const unsigned char*)d_in[7];
    int n = in_sizes[0] / 3;
    float* out = (float*)d_out;
    float* out_tail = out + (size_t)n * 5;   // surface_tf (16) + next_tf (16)
    Params* params = (Params*)d_ws;

    setup_kernel<<<1, 1, 0, stream>>>(tf, diameter, C, anchors, scale, normalize,
                                      out_tail, params);
    int threads = 256;
    int nthreads = (n + 3) / 4;
    int blocks = (nthreads + threads - 1) / threads;
    trace_kernel<<<blocks, threads, 0, stream>>>(P, V, params, out, n);
}

// Round 4
// 177.106 us; speedup vs baseline: 1.1556x; 1.0192x over previous
//
#include <hip/hip_runtime.h>

#define F_EPS 1e-12f
#define F_DAMPING 0.95f
#define N_ITER 6
#define TPB 256

// Single fused kernel.
//  - Params computed per-block from the scalar inputs (uniform -> scalar ALU);
//    block 0 also writes the surface_tf/next_tf output tail (32 floats).
//  - All global loads/stores are lane-contiguous float4 (1 KiB per wave instr);
//    the AoS<->SoA redistribution goes through a 12 KB LDS buffer reused for
//    P-in, V-in, and normals-out (stride-3-float4 LDS access = 2-way alias, free).
//  - Newton loop: it OUTER / ray INNER, hw rcp/rsq, explicit fmaf.
__launch_bounds__(TPB)
__global__ void trace_kernel(const float* __restrict__ P,
                             const float* __restrict__ V,
                             const float* __restrict__ tf,
                             const float* __restrict__ diameter,
                             const float* __restrict__ Cc,
                             const float* __restrict__ anchors,
                             const float* __restrict__ scale_p,
                             const unsigned char* __restrict__ normalize,
                             float* __restrict__ out,
                             int n)
{
    __shared__ float4 sbuf[TPB * 3];   // 12 KB
    const int tid  = threadIdx.x;
    const int base = (blockIdx.x * TPB + tid) * 4;   // first ray of this thread

    // ---- uniform params (precise, contraction off; matches reference order) ----
    float R0,R1,R2,R3,R4,R5,R6,R7,R8, tv0,tv1,tv2;
    float C_eff, scale, half_d2, inv_s2;
    {
#pragma clang fp contract(off)
        float d  = diameter[0];
        float c  = Cc[0];
        float sc = scale_p[0];
        bool  nrm = (normalize[0] != 0);
        C_eff = nrm ? (c * 2.0f / d) : c;
        float s2 = sc * sc;
        float hr = d * 0.5f;
        half_d2 = hr * hr;
        float u = half_d2 / s2;
        float root = sqrtf(fmaxf(1.0f - (C_eff * C_eff) * u, F_EPS));
        float extent = sc * C_eff * u / (1.0f + root);
        float a0 = anchors[0], a1 = anchors[1];
        float dx0 = -a0 * extent;
        float dx1 = (a1 - a0) * extent;
        R0 = tf[0]; R1 = tf[1]; R2 = tf[2];
        R3 = tf[4]; R4 = tf[5]; R5 = tf[6];
        R6 = tf[8]; R7 = tf[9]; R8 = tf[10];
        tv0 = tf[0] * dx0 + tf[3];
        tv1 = tf[4] * dx0 + tf[7];
        tv2 = tf[8] * dx0 + tf[11];
        scale  = sc;
        inv_s2 = 1.0f / s2;
        if (blockIdx.x == 0 && tid < 16) {
            int i = tid >> 2, j = tid & 3;
            float v  = tf[tid];
            float sv = (j == 3) ? (tf[i * 4] * dx0 + v) : v;
            float nv = (j == 3) ? (tf[i * 4] * dx1 + v) : v;
            float* out_tail = out + (size_t)n * 5;
            out_tail[tid]      = sv;
            out_tail[16 + tid] = nv;
        }
    }
    float ce2   = C_eff * C_eff;
    float sC    = scale * C_eff;
    float a_num = sC * inv_s2;          // F = a_num*r2/(1+root) - p.x
    float ce2s  = ce2 * inv_s2;         // m = 1 - ce2s*r2
    float Cs    = C_eff / scale;        // k = Cs * rsq(m)

    const bool full_block = ((blockIdx.x + 1) * (TPB * 4) <= n);  // block-uniform

    float Px[4], Py[4], Pz[4], Vx[4], Vy[4], Vz[4];
    if (full_block) {
        const size_t bf4 = (size_t)blockIdx.x * (TPB * 3);
        const float4* P4 = reinterpret_cast<const float4*>(P);
        const float4* V4 = reinterpret_cast<const float4*>(V);
        // all 6 contiguous loads issued up-front (max MLP)
        float4 p0 = P4[bf4 + tid], p1 = P4[bf4 + TPB + tid], p2 = P4[bf4 + 2*TPB + tid];
        float4 q0 = V4[bf4 + tid], q1 = V4[bf4 + TPB + tid], q2 = V4[bf4 + 2*TPB + tid];
        // stage P
        sbuf[tid] = p0; sbuf[TPB + tid] = p1; sbuf[2*TPB + tid] = p2;
        __syncthreads();
        float4 a = sbuf[3*tid], b = sbuf[3*tid + 1], c = sbuf[3*tid + 2];
        __syncthreads();
        Px[0]=a.x; Py[0]=a.y; Pz[0]=a.z; Px[1]=a.w; Py[1]=b.x; Pz[1]=b.y;
        Px[2]=b.z; Py[2]=b.w; Pz[2]=c.x; Px[3]=c.y; Py[3]=c.z; Pz[3]=c.w;
        // stage V
        sbuf[tid] = q0; sbuf[TPB + tid] = q1; sbuf[2*TPB + tid] = q2;
        __syncthreads();
        a = sbuf[3*tid]; b = sbuf[3*tid + 1]; c = sbuf[3*tid + 2];
        __syncthreads();
        Vx[0]=a.x; Vy[0]=a.y; Vz[0]=a.z; Vx[1]=a.w; Vy[1]=b.x; Vz[1]=b.y;
        Vx[2]=b.z; Vy[2]=b.w; Vz[2]=c.x; Vx[3]=c.y; Vy[3]=c.z; Vz[3]=c.w;
    } else {
        for (int r = 0; r < 4; ++r) {
            int i = base + r;
            if (i < n) {
                Px[r] = P[(size_t)i*3 + 0]; Py[r] = P[(size_t)i*3 + 1]; Pz[r] = P[(size_t)i*3 + 2];
                Vx[r] = V[(size_t)i*3 + 0]; Vy[r] = V[(size_t)i*3 + 1]; Vz[r] = V[(size_t)i*3 + 2];
            } else {
                Px[r] = 0.0f; Py[r] = 0.0f; Pz[r] = 0.0f;
                Vx[r] = 1.0f; Vy[r] = 0.0f; Vz[r] = 0.0f;
            }
        }
    }

    // ---- transform to local frame (SoA state, all 4 rays live) ----
    float Plx[4], Ply[4], Plz[4], vx[4], vy[4], vz[4], tN[4];
#pragma unroll
    for (int r = 0; r < 4; ++r) {
        float px0 = Px[r] - tv0, py0 = Py[r] - tv1, pz0 = Pz[r] - tv2;
        Plx[r] = px0 * R0 + py0 * R3 + pz0 * R6;
        Ply[r] = px0 * R1 + py0 * R4 + pz0 * R7;
        Plz[r] = px0 * R2 + py0 * R5 + pz0 * R8;
        vx[r] = Vx[r] * R0 + Vy[r] * R3 + Vz[r] * R6;
        vy[r] = Vx[r] * R1 + Vy[r] * R4 + Vz[r] * R7;
        vz[r] = Vx[r] * R2 + Vy[r] * R5 + Vz[r] * R8;
        float safe_vx = (fabsf(vx[r]) > F_EPS) ? vx[r] : F_EPS;
        tN[r] = (-Plx[r]) * __builtin_amdgcn_rcpf(safe_vx);
    }

    // ---- Newton: it OUTER, ray INNER ----
#pragma unroll
    for (int it = 0; it < N_ITER; ++it) {
#pragma unroll
        for (int r = 0; r < 4; ++r) {
            float pxx = fmaf(tN[r], vx[r], Plx[r]);
            float py  = fmaf(tN[r], vy[r], Ply[r]);
            float pz  = fmaf(tN[r], vz[r], Plz[r]);
            float r2  = fmaf(py, py, pz * pz);
            float m   = fmaxf(fmaf(-ce2s, r2, 1.0f), F_EPS);
            float rsq = __builtin_amdgcn_rsqf(m);
            float root = m * rsq;
            float k    = Cs * rsq;
            float ird  = __builtin_amdgcn_rcpf(1.0f + root);
            float F    = fmaf(a_num * r2, ird, -pxx);
            float dF = fmaf(k * py, vy[r], fmaf(k * pz, vz[r], -vx[r]));
            dF = (fabsf(dF) > F_EPS) ? dF : F_EPS;
            tN[r] = fmaf(-F_DAMPING * F, __builtin_amdgcn_rcpf(dF), tN[r]);
        }
    }

    // ---- epilogue ----
    float tres[4], nxo[4], nyo[4], nzo[4], val[4];
#pragma unroll
    for (int r = 0; r < 4; ++r) {
        float pxx = fmaf(tN[r], vx[r], Plx[r]);
        float py  = fmaf(tN[r], vy[r], Ply[r]);
        float pz  = fmaf(tN[r], vz[r], Plz[r]);
        float r2  = fmaf(py, py, pz * pz);
        float m   = fmaxf(fmaf(-ce2s, r2, 1.0f), F_EPS);
        float rsq = __builtin_amdgcn_rsqf(m);
        float root = m * rsq;
        float k    = Cs * rsq;
        float ird  = __builtin_amdgcn_rcpf(1.0f + root);
        float F    = fmaf(a_num * r2, ird, -pxx);
        float gy = k * py, gz = k * pz;
        float nn2 = fmaf(gy, gy, fmaf(gz, gz, 1.0f));
        float irn = __builtin_amdgcn_rsqf(nn2);
        float nlx = -irn, nly = gy * irn, nlz = gz * irn;
        nxo[r] = nlx * R0 + nly * R1 + nlz * R2;
        nyo[r] = nlx * R3 + nly * R4 + nlz * R5;
        nzo[r] = nlx * R6 + nly * R7 + nlz * R8;
        tres[r] = tN[r];
        val[r]  = ((r2 <= half_d2) && (fabsf(F) < 1e-4f)) ? 1.0f : 0.0f;
    }

    float* t_out = out;
    float* n_out = out + (size_t)n;
    float* v_out = out + (size_t)n * 4;
    if (full_block) {
        // stage normals through LDS -> contiguous stores
        sbuf[3*tid]     = make_float4(nxo[0], nyo[0], nzo[0], nxo[1]);
        sbuf[3*tid + 1] = make_float4(nyo[1], nzo[1], nxo[2], nyo[2]);
        sbuf[3*tid + 2] = make_float4(nzo[2], nxo[3], nyo[3], nzo[3]);
        __syncthreads();
        const size_t bf4 = (size_t)blockIdx.x * (TPB * 3);
        float4* N4 = reinterpret_cast<float4*>(n_out);
        N4[bf4 + tid]         = sbuf[tid];
        N4[bf4 + TPB + tid]   = sbuf[TPB + tid];
        N4[bf4 + 2*TPB + tid] = sbuf[2*TPB + tid];
        *reinterpret_cast<float4*>(t_out + base) = make_float4(tres[0], tres[1], tres[2], tres[3]);
        *reinterpret_cast<float4*>(v_out + base) = make_float4(val[0], val[1], val[2], val[3]);
    } else {
        for (int r = 0; r < 4; ++r) {
            int i = base + r;
            if (i < n) {
                t_out[i] = tres[r];
                n_out[(size_t)i*3 + 0] = nxo[r];
                n_out[(size_t)i*3 + 1] = nyo[r];
                n_out[(size_t)i*3 + 2] = nzo[r];
                v_out[i] = val[r];
            }
        }
    }
}

extern "C" void kernel_launch(void* const* d_in, const int* in_sizes, int n_in,
                              void* d_out, int out_size, void* d_ws, size_t ws_size,
                              hipStream_t stream) {
    const float* P  = (const float*)d_in[0];
    const float* V  = (const float*)d_in[1];
    const float* tf = (const float*)d_in[2];
    const float* diameter = (const float*)d_in[3];
    const float* C  = (const float*)d_in[4];
    const float* anchors = (const float*)d_in[5];
    const float* scale = (const float*)d_in[6];
    const unsigned char* normalize = (const unsigned char*)d_in[7];
    int n = in_sizes[0] / 3;
    float* out = (float*)d_out;

    int rays_per_block = TPB * 4;
    int blocks = (n + rays_per_block - 1) / rays_per_block;
    trace_kernel<<<blocks, TPB, 0, stream>>>(P, V, tf, diameter, C, anchors, scale,
                                             normalize, out, n);
}